// Round 1
// baseline (367.836 us; speedup 1.0000x reference)
//
#include <hip/hip_runtime.h>

#define GRIDSZ 13
#define NANCH  5
#define NCLS   20
#define NCHAN  25
#define BATCH  2048
#define NOBJ   32
#define PLANE  (GRIDSZ * GRIDSZ)        // 169
#define NTOT   (BATCH * NOBJ)           // 65536
#define STOT   (BATCH * NANCH * PLANE)  // 1,730,560

// ANCHORS / 13, folded at compile time in IEEE f32 (matches JAX runtime division)
__constant__ float AW[NANCH] = {1.3221f / 13.0f, 3.19275f / 13.0f, 5.05587f / 13.0f,
                                9.47112f / 13.0f, 11.2364f / 13.0f};
__constant__ float AH[NANCH] = {1.73145f / 13.0f, 4.00944f / 13.0f, 8.09892f / 13.0f,
                                4.84053f / 13.0f, 10.0071f / 13.0f};

// Phase (a): per-GT anchor assignment (IoU argmax) + scatter-max of GT index.
__global__ void assign_kernel(const float* __restrict__ det,
                              const float* __restrict__ gt_boxes,
                              int* __restrict__ owner) {
    int n = blockIdx.x * blockDim.x + threadIdx.x;
    if (n >= NTOT) return;
    int b = n / NOBJ;
    float x = gt_boxes[n * 4 + 0];
    float y = gt_boxes[n * 4 + 1];
    float w = gt_boxes[n * 4 + 2];
    float h = gt_boxes[n * 4 + 3];
    int gx = (int)floorf(x * (float)GRIDSZ);
    int gy = (int)floorf(y * (float)GRIDSZ);

    float gx0 = x - w * 0.5f, gy0 = y - h * 0.5f;
    float gx1 = x + w * 0.5f, gy1 = y + h * 0.5f;
    float a1 = (gx1 - gx0 + 1.0f) * (gy1 - gy0 + 1.0f);

    const float* base = det + (size_t)b * (NANCH * NCHAN) * PLANE + gy * GRIDSZ + gx;

    float best = -INFINITY;
    int aidx = 0;
    #pragma unroll
    for (int a = 0; a < NANCH; ++a) {
        const float* p = base + (size_t)a * NCHAN * PLANE;
        float px = p[0];
        float py = p[PLANE];
        float pw = p[2 * PLANE] * AW[a];
        float ph = p[3 * PLANE] * AH[a];
        float bx0 = (px + (float)gx) / 13.0f - pw * 0.5f;
        float by0 = (py + (float)gy) / 13.0f - ph * 0.5f;
        float bx1 = bx0 + pw, by1 = by0 + ph;
        float ix0 = fmaxf(gx0, bx0), iy0 = fmaxf(gy0, by0);
        float ix1 = fminf(gx1, bx1), iy1 = fminf(gy1, by1);
        float inter = (ix1 - ix0 + 1.0f) * (iy1 - iy0 + 1.0f);
        float a2 = (bx1 - bx0 + 1.0f) * (by1 - by0 + 1.0f);
        float iou = inter / (a1 + a2 - inter);
        if (iou > best) { best = iou; aidx = a; }  // first-max (jnp.argmax)
    }
    int flat = ((b * NANCH + aidx) * GRIDSZ + gy) * GRIDSZ + gx;
    atomicMax(&owner[flat], n);
}

// Phase (b): per-cell weighted SE + global reduction into out[0..3].
__global__ void loss_kernel(const float* __restrict__ det,
                            const float* __restrict__ gt_boxes,
                            const int* __restrict__ gt_class,
                            const int* __restrict__ owner,
                            float* __restrict__ out) {
    int s = blockIdx.x * blockDim.x + threadIdx.x;
    float loss = 0.0f, objl = 0.0f, noobjl = 0.0f, confl = 0.0f;
    if (s < STOT) {
        int gx = s % GRIDSZ;
        int gy = (s / GRIDSZ) % GRIDSZ;
        int a  = (s / PLANE) % NANCH;
        int b  = s / (PLANE * NANCH);
        const float* p = det + ((size_t)(b * NANCH + a) * NCHAN) * PLANE + gy * GRIDSZ + gx;
        int o = owner[s];
        if (o < 0) {
            // invalid cell: only channel-4 term contributes (weight 0.5, target 0)
            float d4 = p[4 * PLANE];
            float l = 0.5f * d4 * d4;
            loss = l;
            noobjl = l;
        } else {
            float x = gt_boxes[o * 4 + 0];
            float y = gt_boxes[o * 4 + 1];
            float w = gt_boxes[o * 4 + 2];
            float h = gt_boxes[o * 4 + 3];
            int cls = gt_class[o];
            float tx = x * 13.0f - (float)gx;
            float ty = y * 13.0f - (float)gy;
            float d0 = p[0];
            float d1 = p[PLANE];
            float d2 = p[2 * PLANE] * AW[a];
            float d3 = p[3 * PLANE] * AH[a];
            float d4 = p[4 * PLANE];
            float e, t;
            e = tx - d0; t = 5.0f * e * e; loss += t; objl += t;
            e = ty - d1; t = 5.0f * e * e; loss += t; objl += t;
            e = w  - d2; t = 5.0f * e * e; loss += t; objl += t;
            e = h  - d3; t = 5.0f * e * e; loss += t; objl += t;
            e = 1.0f - d4; t = e * e;      loss += t; objl += t;
            #pragma unroll
            for (int c = 5; c < NCHAN; ++c) {
                float gtv = (c - 5 == cls) ? 1.0f : 0.0f;
                e = gtv - p[c * PLANE];
                t = e * e;
                loss += t;
                confl += t;
            }
        }
    }
    // wave reduce (64 lanes)
    #pragma unroll
    for (int off = 32; off > 0; off >>= 1) {
        loss   += __shfl_down(loss, off);
        objl   += __shfl_down(objl, off);
        noobjl += __shfl_down(noobjl, off);
        confl  += __shfl_down(confl, off);
    }
    __shared__ float sm[4][4];
    int lane = threadIdx.x & 63;
    int wid  = threadIdx.x >> 6;
    if (lane == 0) {
        sm[wid][0] = loss; sm[wid][1] = objl; sm[wid][2] = noobjl; sm[wid][3] = confl;
    }
    __syncthreads();
    if (threadIdx.x == 0) {
        float s0 = 0, s1 = 0, s2 = 0, s3 = 0;
        #pragma unroll
        for (int i = 0; i < 4; ++i) {
            s0 += sm[i][0]; s1 += sm[i][1]; s2 += sm[i][2]; s3 += sm[i][3];
        }
        atomicAdd(&out[0], s0);
        atomicAdd(&out[1], s1);
        atomicAdd(&out[2], s2);
        atomicAdd(&out[3], s3);
    }
}

extern "C" void kernel_launch(void* const* d_in, const int* in_sizes, int n_in,
                              void* d_out, int out_size, void* d_ws, size_t ws_size,
                              hipStream_t stream) {
    const float* det = (const float*)d_in[0];
    const float* gtb = (const float*)d_in[1];
    const int*   gtc = (const int*)d_in[2];
    float* out = (float*)d_out;
    int* owner = (int*)d_ws;  // STOT ints = ~6.9 MB

    hipMemsetAsync(owner, 0xFF, (size_t)STOT * sizeof(int), stream);  // -1
    hipMemsetAsync(out, 0, 4 * sizeof(float), stream);

    assign_kernel<<<(NTOT + 255) / 256, 256, 0, stream>>>(det, gtb, owner);
    loss_kernel<<<(STOT + 255) / 256, 256, 0, stream>>>(det, gtb, gtc, owner, out);
}

// Round 2
// 40.999 us; speedup vs baseline: 8.9719x; 8.9719x over previous
//
#include <hip/hip_runtime.h>

#define GRIDSZ 13
#define NANCH  5
#define NCLS   20
#define NCHAN  25
#define BATCH  2048
#define NOBJ   32
#define PLANE  (GRIDSZ * GRIDSZ)        // 169
#define NTOT   (BATCH * NOBJ)           // 65536
#define STOT   (BATCH * NANCH * PLANE)  // 1,730,560
#define LBLOCKS 1024                    // loss_kernel grid; partials in ws

// ANCHORS / 13, folded at compile time in IEEE f32 (matches JAX runtime division)
__constant__ float AW[NANCH] = {1.3221f / 13.0f, 3.19275f / 13.0f, 5.05587f / 13.0f,
                                9.47112f / 13.0f, 11.2364f / 13.0f};
__constant__ float AH[NANCH] = {1.73145f / 13.0f, 4.00944f / 13.0f, 8.09892f / 13.0f,
                                4.84053f / 13.0f, 10.0071f / 13.0f};

// Phase (a): per-GT anchor assignment (IoU argmax) + scatter-max of GT index.
__global__ void assign_kernel(const float* __restrict__ det,
                              const float* __restrict__ gt_boxes,
                              int* __restrict__ owner) {
    int n = blockIdx.x * blockDim.x + threadIdx.x;
    if (n >= NTOT) return;
    int b = n / NOBJ;
    float x = gt_boxes[n * 4 + 0];
    float y = gt_boxes[n * 4 + 1];
    float w = gt_boxes[n * 4 + 2];
    float h = gt_boxes[n * 4 + 3];
    int gx = (int)floorf(x * (float)GRIDSZ);
    int gy = (int)floorf(y * (float)GRIDSZ);

    float gx0 = x - w * 0.5f, gy0 = y - h * 0.5f;
    float gx1 = x + w * 0.5f, gy1 = y + h * 0.5f;
    float a1 = (gx1 - gx0 + 1.0f) * (gy1 - gy0 + 1.0f);

    const float* base = det + (size_t)b * (NANCH * NCHAN) * PLANE + gy * GRIDSZ + gx;

    float best = -INFINITY;
    int aidx = 0;
    #pragma unroll
    for (int a = 0; a < NANCH; ++a) {
        const float* p = base + (size_t)a * NCHAN * PLANE;
        float px = p[0];
        float py = p[PLANE];
        float pw = p[2 * PLANE] * AW[a];
        float ph = p[3 * PLANE] * AH[a];
        float bx0 = (px + (float)gx) / 13.0f - pw * 0.5f;
        float by0 = (py + (float)gy) / 13.0f - ph * 0.5f;
        float bx1 = bx0 + pw, by1 = by0 + ph;
        float ix0 = fmaxf(gx0, bx0), iy0 = fmaxf(gy0, by0);
        float ix1 = fminf(gx1, bx1), iy1 = fminf(gy1, by1);
        float inter = (ix1 - ix0 + 1.0f) * (iy1 - iy0 + 1.0f);
        float a2 = (bx1 - bx0 + 1.0f) * (by1 - by0 + 1.0f);
        float iou = inter / (a1 + a2 - inter);
        if (iou > best) { best = iou; aidx = a; }  // first-max (jnp.argmax)
    }
    int flat = ((b * NANCH + aidx) * GRIDSZ + gy) * GRIDSZ + gx;
    atomicMax(&owner[flat], n);
}

// Phase (b): grid-stride per-cell weighted SE; ONE float4 partial per block (no atomics).
__global__ void loss_kernel(const float* __restrict__ det,
                            const float* __restrict__ gt_boxes,
                            const int* __restrict__ gt_class,
                            const int* __restrict__ owner,
                            float4* __restrict__ partials) {
    float loss = 0.0f, objl = 0.0f, noobjl = 0.0f, confl = 0.0f;
    int stride = LBLOCKS * 256;
    for (int s = blockIdx.x * 256 + threadIdx.x; s < STOT; s += stride) {
        int gx = s % GRIDSZ;
        int gy = (s / GRIDSZ) % GRIDSZ;
        int a  = (s / PLANE) % NANCH;
        int b  = s / (PLANE * NANCH);
        const float* p = det + ((size_t)(b * NANCH + a) * NCHAN) * PLANE + gy * GRIDSZ + gx;
        int o = owner[s];
        if (o < 0) {
            // invalid cell: only channel-4 term contributes (weight 0.5, target 0)
            float d4 = p[4 * PLANE];
            float l = 0.5f * d4 * d4;
            loss += l;
            noobjl += l;
        } else {
            float x = gt_boxes[o * 4 + 0];
            float y = gt_boxes[o * 4 + 1];
            float w = gt_boxes[o * 4 + 2];
            float h = gt_boxes[o * 4 + 3];
            int cls = gt_class[o];
            float tx = x * 13.0f - (float)gx;
            float ty = y * 13.0f - (float)gy;
            float d0 = p[0];
            float d1 = p[PLANE];
            float d2 = p[2 * PLANE] * AW[a];
            float d3 = p[3 * PLANE] * AH[a];
            float d4 = p[4 * PLANE];
            float e, t;
            e = tx - d0; t = 5.0f * e * e; loss += t; objl += t;
            e = ty - d1; t = 5.0f * e * e; loss += t; objl += t;
            e = w  - d2; t = 5.0f * e * e; loss += t; objl += t;
            e = h  - d3; t = 5.0f * e * e; loss += t; objl += t;
            e = 1.0f - d4; t = e * e;      loss += t; objl += t;
            #pragma unroll
            for (int c = 5; c < NCHAN; ++c) {
                float gtv = (c - 5 == cls) ? 1.0f : 0.0f;
                e = gtv - p[c * PLANE];
                t = e * e;
                loss += t;
                confl += t;
            }
        }
    }
    // wave reduce (64 lanes)
    #pragma unroll
    for (int off = 32; off > 0; off >>= 1) {
        loss   += __shfl_down(loss, off);
        objl   += __shfl_down(objl, off);
        noobjl += __shfl_down(noobjl, off);
        confl  += __shfl_down(confl, off);
    }
    __shared__ float sm[4][4];
    int lane = threadIdx.x & 63;
    int wid  = threadIdx.x >> 6;
    if (lane == 0) {
        sm[wid][0] = loss; sm[wid][1] = objl; sm[wid][2] = noobjl; sm[wid][3] = confl;
    }
    __syncthreads();
    if (threadIdx.x == 0) {
        float s0 = 0, s1 = 0, s2 = 0, s3 = 0;
        #pragma unroll
        for (int i = 0; i < 4; ++i) {
            s0 += sm[i][0]; s1 += sm[i][1]; s2 += sm[i][2]; s3 += sm[i][3];
        }
        partials[blockIdx.x] = make_float4(s0, s1, s2, s3);
    }
}

// Final: one block sums LBLOCKS float4 partials and writes out[0..3].
__global__ void reduce_kernel(const float4* __restrict__ partials,
                              float* __restrict__ out) {
    float s0 = 0, s1 = 0, s2 = 0, s3 = 0;
    for (int i = threadIdx.x; i < LBLOCKS; i += 256) {
        float4 v = partials[i];
        s0 += v.x; s1 += v.y; s2 += v.z; s3 += v.w;
    }
    #pragma unroll
    for (int off = 32; off > 0; off >>= 1) {
        s0 += __shfl_down(s0, off);
        s1 += __shfl_down(s1, off);
        s2 += __shfl_down(s2, off);
        s3 += __shfl_down(s3, off);
    }
    __shared__ float sm[4][4];
    int lane = threadIdx.x & 63;
    int wid  = threadIdx.x >> 6;
    if (lane == 0) {
        sm[wid][0] = s0; sm[wid][1] = s1; sm[wid][2] = s2; sm[wid][3] = s3;
    }
    __syncthreads();
    if (threadIdx.x == 0) {
        float a0 = 0, a1 = 0, a2 = 0, a3 = 0;
        #pragma unroll
        for (int i = 0; i < 4; ++i) {
            a0 += sm[i][0]; a1 += sm[i][1]; a2 += sm[i][2]; a3 += sm[i][3];
        }
        out[0] = a0; out[1] = a1; out[2] = a2; out[3] = a3;
    }
}

extern "C" void kernel_launch(void* const* d_in, const int* in_sizes, int n_in,
                              void* d_out, int out_size, void* d_ws, size_t ws_size,
                              hipStream_t stream) {
    const float* det = (const float*)d_in[0];
    const float* gtb = (const float*)d_in[1];
    const int*   gtc = (const int*)d_in[2];
    float* out = (float*)d_out;
    int* owner = (int*)d_ws;                                    // STOT ints = ~6.9 MB
    float4* partials = (float4*)((char*)d_ws + (size_t)STOT * sizeof(int)); // 16 KB

    hipMemsetAsync(owner, 0xFF, (size_t)STOT * sizeof(int), stream);  // -1

    assign_kernel<<<(NTOT + 255) / 256, 256, 0, stream>>>(det, gtb, owner);
    loss_kernel<<<LBLOCKS, 256, 0, stream>>>(det, gtb, gtc, owner, partials);
    reduce_kernel<<<1, 256, 0, stream>>>(partials, out);
}

// Round 3
// 32.512 us; speedup vs baseline: 11.3139x; 1.2610x over previous
//
#include <hip/hip_runtime.h>

#define GRIDSZ 13
#define NANCH  5
#define NCHAN  25
#define BATCH  2048
#define NOBJ   32
#define PLANE  (GRIDSZ * GRIDSZ)        // 169
#define NTOT   (BATCH * NOBJ)           // 65536
#define NCHUNK (BATCH * NANCH)          // 10240 (b,a) chunks
#define ABLOCKS 256                     // GT-assignment blocks (256*256 = NTOT)
#define BBLOCKS 256                     // baseline-reduction blocks
#define TBLOCKS (ABLOCKS + BBLOCKS)

// ANCHORS / 13, folded at compile time in IEEE f32 (matches JAX runtime division)
__constant__ float AW[NANCH] = {1.3221f / 13.0f, 3.19275f / 13.0f, 5.05587f / 13.0f,
                                9.47112f / 13.0f, 11.2364f / 13.0f};
__constant__ float AH[NANCH] = {1.73145f / 13.0f, 4.00944f / 13.0f, 8.09892f / 13.0f,
                                4.84053f / 13.0f, 10.0071f / 13.0f};

// Fused kernel.
//  Blocks [0, ABLOCKS):   per-GT anchor assignment + in-LDS winner resolution +
//                         correction terms (full wse - baseline ch4 term).
//  Blocks [ABLOCKS, ...): baseline  sum of 0.5*d4^2 over ALL cells (coalesced ch-4 planes).
// Each block writes one float4 partial {d_loss, obj, d_noobj, conf}.
__global__ void main_kernel(const float* __restrict__ det,
                            const float* __restrict__ gt_boxes,
                            const int* __restrict__ gt_class,
                            float4* __restrict__ partials) {
    __shared__ int flats[256];
    __shared__ float sm[4][4];
    float loss = 0.0f, objl = 0.0f, noobjl = 0.0f, confl = 0.0f;

    if (blockIdx.x < ABLOCKS) {
        int n = blockIdx.x * 256 + threadIdx.x;       // GT index, exact cover of NTOT
        int b = n >> 5;                               // batch (NOBJ = 32)
        float4 g = ((const float4*)gt_boxes)[n];      // (x,y,w,h) vector load
        float x = g.x, y = g.y, w = g.z, h = g.w;
        int gx = (int)floorf(x * 13.0f);
        int gy = (int)floorf(y * 13.0f);

        float gx0 = x - w * 0.5f, gy0 = y - h * 0.5f;
        float gx1 = x + w * 0.5f, gy1 = y + h * 0.5f;
        float a1 = (gx1 - gx0 + 1.0f) * (gy1 - gy0 + 1.0f);

        const float* cell = det + (size_t)b * (NANCH * NCHAN) * PLANE + gy * GRIDSZ + gx;

        float best = -INFINITY;
        int aidx = 0;
        float c0 = 0.f, c1 = 0.f, c2 = 0.f, c3 = 0.f;  // winning anchor ch0-3 (scaled)
        #pragma unroll
        for (int a = 0; a < NANCH; ++a) {
            const float* p = cell + (size_t)a * NCHAN * PLANE;
            float px = p[0];
            float py = p[PLANE];
            float pw = p[2 * PLANE] * AW[a];
            float ph = p[3 * PLANE] * AH[a];
            float bx0 = (px + (float)gx) / 13.0f - pw * 0.5f;
            float by0 = (py + (float)gy) / 13.0f - ph * 0.5f;
            float bx1 = bx0 + pw, by1 = by0 + ph;
            float ix0 = fmaxf(gx0, bx0), iy0 = fmaxf(gy0, by0);
            float ix1 = fminf(gx1, bx1), iy1 = fminf(gy1, by1);
            float inter = (ix1 - ix0 + 1.0f) * (iy1 - iy0 + 1.0f);
            float a2 = (bx1 - bx0 + 1.0f) * (by1 - by0 + 1.0f);
            float iou = inter / (a1 + a2 - inter);
            if (iou > best) { best = iou; aidx = a; c0 = px; c1 = py; c2 = pw; c3 = ph; }
        }
        int flat = ((b * NANCH + aidx) * GRIDSZ + gy) * GRIDSZ + gx;

        // winner = no higher-index GT in the SAME batch with the same slot
        flats[threadIdx.x] = flat;
        __syncthreads();
        int o  = threadIdx.x & 31;        // GT-within-batch
        int bb = threadIdx.x & ~31;       // batch base within block
        bool winner = true;
        for (int m = o + 1; m < 32; ++m)
            if (flats[bb + m] == flat) winner = false;

        if (winner) {
            const float* p = cell + (size_t)aidx * NCHAN * PLANE;
            float d4 = p[4 * PLANE];
            int cls = gt_class[n];
            float tx = x * 13.0f - (float)gx;
            float ty = y * 13.0f - (float)gy;
            float e, t, corr = 0.0f;
            e = tx - c0;   t = 5.0f * e * e; corr += t; objl += t;
            e = ty - c1;   t = 5.0f * e * e; corr += t; objl += t;
            e = w  - c2;   t = 5.0f * e * e; corr += t; objl += t;
            e = h  - c3;   t = 5.0f * e * e; corr += t; objl += t;
            e = 1.0f - d4; t = e * e;        corr += t; objl += t;
            #pragma unroll
            for (int c = 5; c < NCHAN; ++c) {
                float gtv = (c - 5 == cls) ? 1.0f : 0.0f;
                e = gtv - p[c * PLANE];
                t = e * e;
                corr += t;
                confl += t;
            }
            float sub = 0.5f * d4 * d4;     // baseline term this owned cell replaces
            loss   = corr - sub;
            noobjl = -sub;
        }
    } else {
        // baseline: sum 0.5*d4^2 over every cell; ch-4 plane of each (b,a) chunk
        int wid = threadIdx.x >> 6, lane = threadIdx.x & 63;
        int wglob = (blockIdx.x - ABLOCKS) * 4 + wid;   // 1024 waves
        float s = 0.0f;
        for (int chunk = wglob; chunk < NCHUNK; chunk += BBLOCKS * 4) {
            const float* p = det + (size_t)chunk * (NCHAN * PLANE) + 4 * PLANE;
            for (int i = lane; i < PLANE; i += 64) {
                float d = p[i];
                s += d * d;
            }
        }
        loss   = 0.5f * s;
        noobjl = 0.5f * s;
    }

    // block reduction -> one float4 partial
    #pragma unroll
    for (int off = 32; off > 0; off >>= 1) {
        loss   += __shfl_down(loss, off);
        objl   += __shfl_down(objl, off);
        noobjl += __shfl_down(noobjl, off);
        confl  += __shfl_down(confl, off);
    }
    int lane = threadIdx.x & 63;
    int wid  = threadIdx.x >> 6;
    __syncthreads();  // protect flats[] reuse boundary / ensure sm ready
    if (lane == 0) {
        sm[wid][0] = loss; sm[wid][1] = objl; sm[wid][2] = noobjl; sm[wid][3] = confl;
    }
    __syncthreads();
    if (threadIdx.x == 0) {
        float s0 = 0, s1 = 0, s2 = 0, s3 = 0;
        #pragma unroll
        for (int i = 0; i < 4; ++i) {
            s0 += sm[i][0]; s1 += sm[i][1]; s2 += sm[i][2]; s3 += sm[i][3];
        }
        partials[blockIdx.x] = make_float4(s0, s1, s2, s3);
    }
}

// Final: one block sums TBLOCKS float4 partials and writes out[0..3].
__global__ void reduce_kernel(const float4* __restrict__ partials,
                              float* __restrict__ out) {
    float s0 = 0, s1 = 0, s2 = 0, s3 = 0;
    for (int i = threadIdx.x; i < TBLOCKS; i += 256) {
        float4 v = partials[i];
        s0 += v.x; s1 += v.y; s2 += v.z; s3 += v.w;
    }
    #pragma unroll
    for (int off = 32; off > 0; off >>= 1) {
        s0 += __shfl_down(s0, off);
        s1 += __shfl_down(s1, off);
        s2 += __shfl_down(s2, off);
        s3 += __shfl_down(s3, off);
    }
    __shared__ float sm[4][4];
    int lane = threadIdx.x & 63;
    int wid  = threadIdx.x >> 6;
    if (lane == 0) {
        sm[wid][0] = s0; sm[wid][1] = s1; sm[wid][2] = s2; sm[wid][3] = s3;
    }
    __syncthreads();
    if (threadIdx.x == 0) {
        float a0 = 0, a1 = 0, a2 = 0, a3 = 0;
        #pragma unroll
        for (int i = 0; i < 4; ++i) {
            a0 += sm[i][0]; a1 += sm[i][1]; a2 += sm[i][2]; a3 += sm[i][3];
        }
        out[0] = a0; out[1] = a1; out[2] = a2; out[3] = a3;
    }
}

extern "C" void kernel_launch(void* const* d_in, const int* in_sizes, int n_in,
                              void* d_out, int out_size, void* d_ws, size_t ws_size,
                              hipStream_t stream) {
    const float* det = (const float*)d_in[0];
    const float* gtb = (const float*)d_in[1];
    const int*   gtc = (const int*)d_in[2];
    float* out = (float*)d_out;
    float4* partials = (float4*)d_ws;   // TBLOCKS * 16 B = 8 KB

    main_kernel<<<TBLOCKS, 256, 0, stream>>>(det, gtb, gtc, partials);
    reduce_kernel<<<1, 256, 0, stream>>>(partials, out);
}